// Round 8
// baseline (417.992 us; speedup 1.0000x reference)
//
#include <hip/hip_runtime.h>
#include <hip/hip_bf16.h>

// MultiHeadSelfAttention: B=4, S=2048, D=1024, H=16, HD=64, fp32 in/out.
// bf16 MFMA. Fused QKV GEMM, flash attention (swapped QK^T, in-register P,
// exp2 softmax, defer-rescale, global_load_lds staging with pre-swizzled
// source -> conflict-free LDS reads), BM=64 out-projection GEMM.

#define B_  4
#define S_  2048
#define D_  1024
#define H_  16
#define HD_ 64
#define M_  (B_*S_)   // 8192 rows
// fold 1/sqrt(HD) and log2(e) into Q so softmax runs in exp2 space
#define QSCALE (0.125f * 1.4426950408889634f)

typedef __attribute__((ext_vector_type(8))) short short8;   // 8 x bf16
typedef __attribute__((ext_vector_type(4))) float f32x4;    // MFMA acc
typedef __hip_bfloat16 bf16;

// ---------------------------------------------------------------- helpers
__device__ inline void gload_lds16(const void* g, void* l) {
  __builtin_amdgcn_global_load_lds(
      (const __attribute__((address_space(1))) void*)g,
      (__attribute__((address_space(3))) void*)l,
      16, 0, 0);
}

__device__ inline f32x4 mfma16(short8 a, short8 b, f32x4 c) {
  return __builtin_amdgcn_mfma_f32_16x16x32_bf16(a, b, c, 0, 0, 0);
}

__device__ inline short bfbits(float f) {
  bf16 h = (bf16)f;
  return *reinterpret_cast<short*>(&h);
}

// ---------------------------------------------------------------- convert x
__global__ void convert_x_kernel(const float* __restrict__ x, bf16* __restrict__ xb) {
  const int i = (blockIdx.x * 256 + threadIdx.x) * 8;
  float4 a = *reinterpret_cast<const float4*>(x + i);
  float4 b = *reinterpret_cast<const float4*>(x + i + 4);
  bf16 o[8];
  o[0] = (bf16)a.x; o[1] = (bf16)a.y; o[2] = (bf16)a.z; o[3] = (bf16)a.w;
  o[4] = (bf16)b.x; o[5] = (bf16)b.y; o[6] = (bf16)b.z; o[7] = (bf16)b.w;
  *reinterpret_cast<int4*>(xb + i) = *reinterpret_cast<const int4*>(o);
}

// ------------------------------------------------- transpose + convert weights
struct TP { const float* w[4]; bf16* wt[4]; };

__global__ void transpose_w_kernel(TP p) {
  const float* w = p.w[blockIdx.z];
  bf16* wt = p.wt[blockIdx.z];
  __shared__ float t[32][33];
  const int k0 = blockIdx.y * 32, n0 = blockIdx.x * 32;
  const int c = threadIdx.x & 31, r4 = threadIdx.x >> 5;
  #pragma unroll
  for (int i = 0; i < 4; ++i) {
    int r = r4 + i * 8;
    t[r][c] = w[(size_t)(k0 + r) * D_ + n0 + c];
  }
  __syncthreads();
  #pragma unroll
  for (int i = 0; i < 4; ++i) {
    int r = r4 + i * 8;
    wt[(size_t)(n0 + r) * D_ + k0 + c] = (bf16)t[c][r];
  }
}

// ------------------------------------------------- fused QKV GEMM
// C[8192,3072] = x[8192,1024] @ Bt3[3072,1024]^T + bias; per-column routing:
// cols [0,1024)->q (scaled by QSCALE), [1024,2048)->k, [2048,3072)->v^T.
// 128x128 tile, BK=32, 4 waves (2x2), grid (24,64) = 1536 blocks (~6/CU).
__global__ __launch_bounds__(256) void gemm_qkv_kernel(
    const bf16* __restrict__ A, const bf16* __restrict__ Bt3,
    const float* __restrict__ bq, const float* __restrict__ bk,
    const float* __restrict__ bv,
    bf16* __restrict__ qb, bf16* __restrict__ kb, bf16* __restrict__ vtb)
{
  constexpr int BK = 32;
  __shared__ __align__(16) bf16 As[128 * BK];
  __shared__ __align__(16) bf16 Bs[128 * BK];
  const int tid = threadIdx.x;
  const int w = tid >> 6, l = tid & 63;
  const int lo = l & 15, hi = l >> 4;
  const int wm = w >> 1, wn = w & 1;
  const int row0 = blockIdx.y * 128;
  const int col0 = blockIdx.x * 128;

  f32x4 acc[4][4] = {};

  for (int kt = 0; kt < D_; kt += BK) {
    __syncthreads();
    #pragma unroll
    for (int i = 0; i < 2; ++i) {
      const int cb = i * 256 + w * 64;
      const int c  = cb + l;
      gload_lds16(A   + (size_t)(row0 + (c >> 2)) * D_ + kt + (c & 3) * 8,
                  (void*)(As + cb * 8));
      gload_lds16(Bt3 + (size_t)(col0 + (c >> 2)) * D_ + kt + (c & 3) * 8,
                  (void*)(Bs + cb * 8));
    }
    __syncthreads();

    short8 a[4], b[4];
    #pragma unroll
    for (int m = 0; m < 4; ++m)
      a[m] = *reinterpret_cast<const short8*>(As + (wm*64 + m*16 + lo) * BK + hi*8);
    #pragma unroll
    for (int n = 0; n < 4; ++n)
      b[n] = *reinterpret_cast<const short8*>(Bs + (wn*64 + n*16 + lo) * BK + hi*8);
    #pragma unroll
    for (int m = 0; m < 4; ++m)
      #pragma unroll
      for (int n = 0; n < 4; ++n)
        acc[m][n] = mfma16(a[m], b[n], acc[m][n]);
  }

  #pragma unroll
  for (int n = 0; n < 4; ++n) {
    const int c3 = col0 + wn*64 + n*16 + lo;          // 0..3071
    const int which = c3 >> 10;                        // 0=q 1=k 2=v
    const int cc = c3 & 1023;
    const int h = cc >> 6, hd = cc & 63;
    const float* bias = (which == 0) ? bq : (which == 1) ? bk : bv;
    const float bvv = bias[cc];
    #pragma unroll
    for (int m = 0; m < 4; ++m) {
      #pragma unroll
      for (int j = 0; j < 4; ++j) {
        const int r = row0 + wm*64 + m*16 + hi*4 + j;
        const int bb = r >> 11, s = r & (S_ - 1);
        float v = acc[m][n][j] + bvv;
        if (which == 0) {
          v *= QSCALE;
          qb[((size_t)(bb * H_ + h) * S_ + s) * HD_ + hd] = (bf16)v;
        } else if (which == 1) {
          kb[((size_t)(bb * H_ + h) * S_ + s) * HD_ + hd] = (bf16)v;
        } else {
          vtb[((size_t)(bb * H_ + h) * HD_ + hd) * S_ + s] = (bf16)v;
        }
      }
    }
  }
}

// ------------------------------------------------- output projection GEMM
// out[8192,1024] fp32 = A[8192,1024] @ Bt^T + bias; 64x128 tile,
// grid (8,128) = 1024 blocks (~4/CU), wave tile 32x64 (2x4 frags).
__global__ __launch_bounds__(256) void gemm_out_kernel(
    const bf16* __restrict__ A, const bf16* __restrict__ Bt,
    const float* __restrict__ bias, float* __restrict__ out)
{
  constexpr int BK = 32;
  __shared__ __align__(16) bf16 As[64 * BK];
  __shared__ __align__(16) bf16 Bs[128 * BK];
  const int tid = threadIdx.x;
  const int w = tid >> 6, l = tid & 63;
  const int lo = l & 15, hi = l >> 4;
  const int wm = w >> 1, wn = w & 1;
  const int row0 = blockIdx.y * 64;
  const int col0 = blockIdx.x * 128;

  f32x4 acc[2][4] = {};

  for (int kt = 0; kt < D_; kt += BK) {
    __syncthreads();
    #pragma unroll
    for (int i = 0; i < 2; ++i) {
      const int cb = i * 256 + w * 64;
      const int c  = cb + l;
      if (i == 0)
        gload_lds16(A + (size_t)(row0 + (c >> 2)) * D_ + kt + (c & 3) * 8,
                    (void*)(As + cb * 8));
      gload_lds16(Bt + (size_t)(col0 + (c >> 2)) * D_ + kt + (c & 3) * 8,
                  (void*)(Bs + cb * 8));
    }
    __syncthreads();

    short8 a[2], b[4];
    #pragma unroll
    for (int m = 0; m < 2; ++m)
      a[m] = *reinterpret_cast<const short8*>(As + (wm*32 + m*16 + lo) * BK + hi*8);
    #pragma unroll
    for (int n = 0; n < 4; ++n)
      b[n] = *reinterpret_cast<const short8*>(Bs + (wn*64 + n*16 + lo) * BK + hi*8);
    #pragma unroll
    for (int m = 0; m < 2; ++m)
      #pragma unroll
      for (int n = 0; n < 4; ++n)
        acc[m][n] = mfma16(a[m], b[n], acc[m][n]);
  }

  #pragma unroll
  for (int n = 0; n < 4; ++n) {
    const int c = col0 + wn*64 + n*16 + lo;
    const float bvv = bias[c];
    #pragma unroll
    for (int m = 0; m < 2; ++m) {
      #pragma unroll
      for (int j = 0; j < 4; ++j) {
        const int r = row0 + wm*32 + m*16 + hi*4 + j;
        out[(size_t)r * D_ + c] = acc[m][n][j] + bvv;
      }
    }
  }
}

// ---------------------------------------------------------------- attention
// 512 blocks (XCD-swizzled: 8 q-blocks of one (b,h) share an XCD's L2).
// 4 waves x 64 q-rows = 256 q/block. K/V tiles of 64 rows x 64 bf16 staged
// DOUBLE-BUFFERED via global_load_lds with PRE-SWIZZLED global source:
// LDS is linear [64][64]; physical 16B slot p of row r holds logical slot
// p ^ (r&7), so strided fragment reads hit distinct banks (2-way max).
// One barrier per tile: prefetch next tile issued right after the barrier,
// drained by the next barrier's implicit vmcnt(0) after a full compute phase.
// Swapped QK^T (S^T = K@Q^T): q is lane-local; softmax = 16 in-lane values
// + 2 shfl, exp2 space (Q pre-scaled by QSCALE), T13 defer-rescale.
__global__ __launch_bounds__(256) void attn_kernel(
    const bf16* __restrict__ q, const bf16* __restrict__ k,
    const bf16* __restrict__ vt, bf16* __restrict__ ao)
{
  __shared__ __align__(16) bf16 Kl[2][64 * 64];
  __shared__ __align__(16) bf16 Vtl[2][64 * 64];   // V^T tile: rows = hd

  const int tid = threadIdx.x;
  const int w = tid >> 6, l = tid & 63;
  const int lo = l & 15, hi = l >> 4;
  // XCD swizzle: 512 blocks, each XCD gets 64 consecutive logical ids
  const int flat = blockIdx.x;
  const int L = (flat & 7) * 64 + (flat >> 3);
  const int bh = L >> 3;                 // 8 q-blocks per bh
  const int q0 = (L & 7) * 256 + w * 64;

  const bf16* kbase = k  + (size_t)bh * S_ * HD_;
  const bf16* vbase = vt + (size_t)bh * HD_ * S_;

  // Q B-frags: lane holds Q[q = n*16+lo][hd = kk*32 + hi*8 .. +8]
  short8 bq[4][2];
  const size_t qrow = (size_t)bh * S_ + q0;
  #pragma unroll
  for (int n = 0; n < 4; ++n)
    #pragma unroll
    for (int kk = 0; kk < 2; ++kk)
      bq[n][kk] = *reinterpret_cast<const short8*>(
          q + (qrow + n*16 + lo) * HD_ + kk*32 + hi*8);

  f32x4 o[4][4] = {};        // o[mm = hd-frag][n = q-frag]
  float mrun[4], lrun[4];
  #pragma unroll
  for (int n = 0; n < 4; ++n) { mrun[n] = -1.0e30f; lrun[n] = 0.0f; }

  // staging lane constants: row-in-8-group and swizzled source slot
  const int sr = l >> 3;               // 0..7
  const int ss = (l & 7) ^ sr;         // logical 16B slot to fetch

  const int r7 = lo & 7;               // row&7 for all fragment rows

  // prologue: stage tile 0 into buffer 0
  #pragma unroll
  for (int i = 0; i < 2; ++i) {
    const int cb = i * 2048 + w * 512;           // wave-uniform elem base
    const int r  = i * 32 + w * 8 + sr;
    gload_lds16(kbase + (size_t)r * HD_ + ss*8, (void*)(&Kl[0][cb]));
    gload_lds16(vbase + (size_t)r * S_  + ss*8, (void*)(&Vtl[0][cb]));
  }
  __syncthreads();

  int cur = 0;
  for (int kt = 0; kt < S_; kt += 64) {
    // prefetch next tile into the other buffer (drained by end-of-tile barrier)
    if (kt + 64 < S_) {
      const int nt = kt + 64;
      #pragma unroll
      for (int i = 0; i < 2; ++i) {
        const int cb = i * 2048 + w * 512;
        const int r  = i * 32 + w * 8 + sr;
        gload_lds16(kbase + (size_t)(nt + r) * HD_ + ss*8, (void*)(&Kl[cur^1][cb]));
        gload_lds16(vbase + (size_t)r * S_ + nt + ss*8,    (void*)(&Vtl[cur^1][cb]));
      }
    }
    const bf16* Kb = &Kl[cur][0];
    const bf16* Vb = &Vtl[cur][0];

    // S^T = K @ Q^T  (K-frag logical slots hi, hi+4 -> swizzled)
    f32x4 s[4][4] = {};
    __builtin_amdgcn_s_setprio(1);
    #pragma unroll
    for (int m = 0; m < 4; ++m) {
      const int row = m*16 + lo;
      short8 kf0 = *reinterpret_cast<const short8*>(Kb + row*64 + ((hi     ^ r7) << 3));
      short8 kf1 = *reinterpret_cast<const short8*>(Kb + row*64 + (((hi+4) ^ r7) << 3));
      #pragma unroll
      for (int n = 0; n < 4; ++n) {
        s[m][n] = mfma16(kf0, bq[n][0], s[m][n]);
        s[m][n] = mfma16(kf1, bq[n][1], s[m][n]);
      }
    }
    __builtin_amdgcn_s_setprio(0);

    // online softmax per q = n*16+lo (exp2 space)
    short8 pb[4][2];
    #pragma unroll
    for (int n = 0; n < 4; ++n) {
      float t0 = fmaxf(fmaxf(s[0][n][0], s[0][n][1]), s[0][n][2]);
      float t1 = fmaxf(fmaxf(s[0][n][3], s[1][n][0]), s[1][n][1]);
      float t2 = fmaxf(fmaxf(s[1][n][2], s[1][n][3]), s[2][n][0]);
      float t3 = fmaxf(fmaxf(s[2][n][1], s[2][n][2]), s[2][n][3]);
      float t4 = fmaxf(fmaxf(s[3][n][0], s[3][n][1]), s[3][n][2]);
      float mx = fmaxf(fmaxf(fmaxf(t0, t1), fmaxf(t2, t3)),
                       fmaxf(t4, s[3][n][3]));
      mx = fmaxf(mx, __shfl_xor(mx, 16, 64));
      mx = fmaxf(mx, __shfl_xor(mx, 32, 64));
      // T13 defer-rescale: skip O/l rescale while max growth <= 8 (2^8 bound)
      float mn;
      if (__all(mx <= mrun[n] + 8.0f)) {
        mn = mrun[n];
      } else {
        mn = fmaxf(mrun[n], mx);
        const float corr = exp2f(mrun[n] - mn);
        lrun[n] *= corr;
        #pragma unroll
        for (int mm = 0; mm < 4; ++mm)
          #pragma unroll
          for (int j = 0; j < 4; ++j)
            o[mm][n][j] *= corr;
        mrun[n] = mn;
      }
      float sum = 0.0f;
      #pragma unroll
      for (int m = 0; m < 4; ++m)
        #pragma unroll
        for (int j = 0; j < 4; ++j) {
          const float p = exp2f(s[m][n][j] - mn);
          s[m][n][j] = p;
          sum += p;
        }
      sum += __shfl_xor(sum, 16, 64);
      sum += __shfl_xor(sum, 32, 64);
      lrun[n] += sum;
      // pack P^T into PV B-operand: slice kk from S^T frags m=2kk, 2kk+1
      #pragma unroll
      for (int kk = 0; kk < 2; ++kk) {
        short8 t;
        t[0] = bfbits(s[2*kk][n][0]);   t[1] = bfbits(s[2*kk][n][1]);
        t[2] = bfbits(s[2*kk][n][2]);   t[3] = bfbits(s[2*kk][n][3]);
        t[4] = bfbits(s[2*kk+1][n][0]); t[5] = bfbits(s[2*kk+1][n][1]);
        t[6] = bfbits(s[2*kk+1][n][2]); t[7] = bfbits(s[2*kk+1][n][3]);
        pb[n][kk] = t;
      }
    }

    // O^T += V^T @ P^T (V-frag: two 8B pieces per 32-slice, swizzled slots)
    __builtin_amdgcn_s_setprio(1);
    #pragma unroll
    for (int mm = 0; mm < 4; ++mm) {
      const int row = mm*16 + lo;
      short8 vf[2];
      #pragma unroll
      for (int kk = 0; kk < 2; ++kk) {
        const int s1 = 4*kk + (hi >> 1);
        const int p1 = s1 ^ r7, p2 = (s1 + 2) ^ r7;
        const int sub = (hi & 1) * 4;
        union { short8 v; uint2 u2[2]; } x;
        x.u2[0] = *reinterpret_cast<const uint2*>(Vb + row*64 + p1*8 + sub);
        x.u2[1] = *reinterpret_cast<const uint2*>(Vb + row*64 + p2*8 + sub);
        vf[kk] = x.v;
      }
      #pragma unroll
      for (int n = 0; n < 4; ++n) {
        o[mm][n] = mfma16(vf[0], pb[n][0], o[mm][n]);
        o[mm][n] = mfma16(vf[1], pb[n][1], o[mm][n]);
      }
    }
    __builtin_amdgcn_s_setprio(0);

    __syncthreads();   // drains prefetch (vmcnt) + protects buffer reuse
    cur ^= 1;
  }

  // normalize + store O^T -> merged-head bf16 [b*S+s][h*64+hd]
  const int b = bh >> 4, h = bh & 15;
  #pragma unroll
  for (int n = 0; n < 4; ++n) {
    const float inv = 1.0f / lrun[n];
    const size_t row = (size_t)b * S_ + q0 + n*16 + lo;
    #pragma unroll
    for (int mm = 0; mm < 4; ++mm) {
      bf16 ov[4];
      #pragma unroll
      for (int j = 0; j < 4; ++j) ov[j] = (bf16)(o[mm][n][j] * inv);
      *reinterpret_cast<uint2*>(ao + row * D_ + h*64 + mm*16 + hi*4) =
          *reinterpret_cast<const uint2*>(ov);
    }
  }
}

// ---------------------------------------------------------------- launch
extern "C" void kernel_launch(void* const* d_in, const int* in_sizes, int n_in,
                              void* d_out, int out_size, void* d_ws, size_t ws_size,
                              hipStream_t stream) {
  const float* x  = (const float*)d_in[0];
  const float* wq = (const float*)d_in[1];
  const float* bq = (const float*)d_in[2];
  const float* wk = (const float*)d_in[3];
  const float* bk = (const float*)d_in[4];
  const float* wv = (const float*)d_in[5];
  const float* bv = (const float*)d_in[6];
  const float* wo = (const float*)d_in[7];
  const float* bo = (const float*)d_in[8];

  char* ws = (char*)d_ws;
  bf16* xb  = (bf16*)(ws);                           // 16 MB: x in bf16
  // wqt/wkt/wvt are contiguous -> usable as one Bt3 [3072][1024] matrix
  bf16* wqt = (bf16*)(ws + ((size_t)16 << 20));      // 2 MB: wq^T bf16
  bf16* wkt = (bf16*)(ws + ((size_t)18 << 20));      // 2 MB: wk^T bf16
  bf16* wvt = (bf16*)(ws + ((size_t)20 << 20));      // 2 MB: wv^T bf16
  bf16* wot = (bf16*)(ws + ((size_t)22 << 20));      // 2 MB: wo^T bf16
  bf16* qb  = (bf16*)(ws + ((size_t)24 << 20));      // 16 MB: q [bh][s][hd] (exp2-scaled)
  bf16* kb  = (bf16*)(ws + ((size_t)40 << 20));      // 16 MB: k [bh][s][hd]
  bf16* vtb = (bf16*)(ws + ((size_t)56 << 20));      // 16 MB: v^T [bh][hd][s]
  bf16* aob = (bf16*)(ws + ((size_t)72 << 20));      // 16 MB: attn out bf16

  convert_x_kernel<<<dim3((M_ * D_) / (256 * 8)), 256, 0, stream>>>(x, xb);

  TP p;
  p.w[0] = wq; p.w[1] = wk; p.w[2] = wv; p.w[3] = wo;
  p.wt[0] = wqt; p.wt[1] = wkt; p.wt[2] = wvt; p.wt[3] = wot;
  transpose_w_kernel<<<dim3(32, 32, 4), 256, 0, stream>>>(p);

  gemm_qkv_kernel<<<dim3(24, 64), 256, 0, stream>>>(
      xb, wqt, bq, bk, bv, qb, kb, vtb);

  attn_kernel<<<dim3(512), 256, 0, stream>>>(qb, kb, vtb, aob);

  gemm_out_kernel<<<dim3(8, 128), 256, 0, stream>>>(aob, wot, bo, (float*)d_out);
}

// Round 9
// 323.887 us; speedup vs baseline: 1.2905x; 1.2905x over previous
//
#include <hip/hip_runtime.h>
#include <hip/hip_bf16.h>

// MultiHeadSelfAttention: B=4, S=2048, D=1024, H=16, HD=64, fp32 in/out.
// bf16 MFMA. Fused QKV GEMM (8192x3072x1024), flash attention in the
// round-2 measured structure (reg-staged KV -> padded LDS, 2 barriers/tile,
// swapped QK^T, in-register P) + exp2-space softmax + defer-rescale.
// BM=64 out-projection GEMM.

#define B_  4
#define S_  2048
#define D_  1024
#define H_  16
#define HD_ 64
#define M_  (B_*S_)   // 8192 rows
// fold 1/sqrt(HD) and log2(e) into Q so softmax runs in exp2 space
#define QSCALE (0.125f * 1.4426950408889634f)

typedef __attribute__((ext_vector_type(8))) short short8;   // 8 x bf16
typedef __attribute__((ext_vector_type(4))) float f32x4;    // MFMA acc
typedef __hip_bfloat16 bf16;

// ---------------------------------------------------------------- helpers
__device__ inline void gload_lds16(const void* g, void* l) {
  __builtin_amdgcn_global_load_lds(
      (const __attribute__((address_space(1))) void*)g,
      (__attribute__((address_space(3))) void*)l,
      16, 0, 0);
}

__device__ inline f32x4 mfma16(short8 a, short8 b, f32x4 c) {
  return __builtin_amdgcn_mfma_f32_16x16x32_bf16(a, b, c, 0, 0, 0);
}

__device__ inline short bfbits(float f) {
  bf16 h = (bf16)f;
  return *reinterpret_cast<short*>(&h);
}

// ---------------------------------------------------------------- convert x
__global__ void convert_x_kernel(const float* __restrict__ x, bf16* __restrict__ xb) {
  const int i = (blockIdx.x * 256 + threadIdx.x) * 8;
  float4 a = *reinterpret_cast<const float4*>(x + i);
  float4 b = *reinterpret_cast<const float4*>(x + i + 4);
  bf16 o[8];
  o[0] = (bf16)a.x; o[1] = (bf16)a.y; o[2] = (bf16)a.z; o[3] = (bf16)a.w;
  o[4] = (bf16)b.x; o[5] = (bf16)b.y; o[6] = (bf16)b.z; o[7] = (bf16)b.w;
  *reinterpret_cast<int4*>(xb + i) = *reinterpret_cast<const int4*>(o);
}

// ------------------------------------------------- transpose + convert weights
struct TP { const float* w[4]; bf16* wt[4]; };

__global__ void transpose_w_kernel(TP p) {
  const float* w = p.w[blockIdx.z];
  bf16* wt = p.wt[blockIdx.z];
  __shared__ float t[32][33];
  const int k0 = blockIdx.y * 32, n0 = blockIdx.x * 32;
  const int c = threadIdx.x & 31, r4 = threadIdx.x >> 5;
  #pragma unroll
  for (int i = 0; i < 4; ++i) {
    int r = r4 + i * 8;
    t[r][c] = w[(size_t)(k0 + r) * D_ + n0 + c];
  }
  __syncthreads();
  #pragma unroll
  for (int i = 0; i < 4; ++i) {
    int r = r4 + i * 8;
    wt[(size_t)(n0 + r) * D_ + k0 + c] = (bf16)t[c][r];
  }
}

// ------------------------------------------------- fused QKV GEMM
// C[8192,3072] = x[8192,1024] @ Bt3[3072,1024]^T + bias; per-column routing:
// cols [0,1024)->q (scaled by QSCALE), [1024,2048)->k, [2048,3072)->v^T.
// 128x128 tile, BK=32, 4 waves (2x2), grid (24,64) = 1536 blocks (~6/CU).
__global__ __launch_bounds__(256) void gemm_qkv_kernel(
    const bf16* __restrict__ A, const bf16* __restrict__ Bt3,
    const float* __restrict__ bq, const float* __restrict__ bk,
    const float* __restrict__ bv,
    bf16* __restrict__ qb, bf16* __restrict__ kb, bf16* __restrict__ vtb)
{
  constexpr int BK = 32;
  __shared__ __align__(16) bf16 As[128 * BK];
  __shared__ __align__(16) bf16 Bs[128 * BK];
  const int tid = threadIdx.x;
  const int w = tid >> 6, l = tid & 63;
  const int lo = l & 15, hi = l >> 4;
  const int wm = w >> 1, wn = w & 1;
  const int row0 = blockIdx.y * 128;
  const int col0 = blockIdx.x * 128;

  f32x4 acc[4][4] = {};

  for (int kt = 0; kt < D_; kt += BK) {
    __syncthreads();
    #pragma unroll
    for (int i = 0; i < 2; ++i) {
      const int cb = i * 256 + w * 64;
      const int c  = cb + l;
      gload_lds16(A   + (size_t)(row0 + (c >> 2)) * D_ + kt + (c & 3) * 8,
                  (void*)(As + cb * 8));
      gload_lds16(Bt3 + (size_t)(col0 + (c >> 2)) * D_ + kt + (c & 3) * 8,
                  (void*)(Bs + cb * 8));
    }
    __syncthreads();

    short8 a[4], b[4];
    #pragma unroll
    for (int m = 0; m < 4; ++m)
      a[m] = *reinterpret_cast<const short8*>(As + (wm*64 + m*16 + lo) * BK + hi*8);
    #pragma unroll
    for (int n = 0; n < 4; ++n)
      b[n] = *reinterpret_cast<const short8*>(Bs + (wn*64 + n*16 + lo) * BK + hi*8);
    #pragma unroll
    for (int m = 0; m < 4; ++m)
      #pragma unroll
      for (int n = 0; n < 4; ++n)
        acc[m][n] = mfma16(a[m], b[n], acc[m][n]);
  }

  #pragma unroll
  for (int n = 0; n < 4; ++n) {
    const int c3 = col0 + wn*64 + n*16 + lo;          // 0..3071
    const int which = c3 >> 10;                        // 0=q 1=k 2=v (wave-uniform)
    const int cc = c3 & 1023;
    const int h = cc >> 6, hd = cc & 63;
    const float* bias = (which == 0) ? bq : (which == 1) ? bk : bv;
    const float bvv = bias[cc];
    if (which == 2) {
      // v^T: j varies s contiguously -> pack 4 bf16 into one 8B store
      #pragma unroll
      for (int m = 0; m < 4; ++m) {
        const int r = row0 + wm*64 + m*16 + hi*4;
        const int bb = r >> 11, s = r & (S_ - 1);
        bf16 ov[4];
        #pragma unroll
        for (int j = 0; j < 4; ++j) ov[j] = (bf16)(acc[m][n][j] + bvv);
        *reinterpret_cast<uint2*>(
            &vtb[((size_t)(bb * H_ + h) * HD_ + hd) * S_ + s]) =
            *reinterpret_cast<const uint2*>(ov);
      }
    } else {
      #pragma unroll
      for (int m = 0; m < 4; ++m) {
        #pragma unroll
        for (int j = 0; j < 4; ++j) {
          const int r = row0 + wm*64 + m*16 + hi*4 + j;
          const int bb = r >> 11, s = r & (S_ - 1);
          float v = acc[m][n][j] + bvv;
          if (which == 0) {
            v *= QSCALE;
            qb[((size_t)(bb * H_ + h) * S_ + s) * HD_ + hd] = (bf16)v;
          } else {
            kb[((size_t)(bb * H_ + h) * S_ + s) * HD_ + hd] = (bf16)v;
          }
        }
      }
    }
  }
}

// ------------------------------------------------- output projection GEMM
// out[8192,1024] fp32 = A[8192,1024] @ Bt^T + bias; 64x128 tile,
// grid (8,128) = 1024 blocks (~4/CU), wave tile 32x64 (2x4 frags).
__global__ __launch_bounds__(256) void gemm_out_kernel(
    const bf16* __restrict__ A, const bf16* __restrict__ Bt,
    const float* __restrict__ bias, float* __restrict__ out)
{
  constexpr int BK = 32;
  __shared__ __align__(16) bf16 As[64 * BK];
  __shared__ __align__(16) bf16 Bs[128 * BK];
  const int tid = threadIdx.x;
  const int w = tid >> 6, l = tid & 63;
  const int lo = l & 15, hi = l >> 4;
  const int wm = w >> 1, wn = w & 1;
  const int row0 = blockIdx.y * 64;
  const int col0 = blockIdx.x * 128;

  f32x4 acc[2][4] = {};

  for (int kt = 0; kt < D_; kt += BK) {
    __syncthreads();
    #pragma unroll
    for (int i = 0; i < 2; ++i) {
      const int cb = i * 256 + w * 64;
      const int c  = cb + l;
      if (i == 0)
        gload_lds16(A + (size_t)(row0 + (c >> 2)) * D_ + kt + (c & 3) * 8,
                    (void*)(As + cb * 8));
      gload_lds16(Bt + (size_t)(col0 + (c >> 2)) * D_ + kt + (c & 3) * 8,
                  (void*)(Bs + cb * 8));
    }
    __syncthreads();

    short8 a[2], b[4];
    #pragma unroll
    for (int m = 0; m < 2; ++m)
      a[m] = *reinterpret_cast<const short8*>(As + (wm*32 + m*16 + lo) * BK + hi*8);
    #pragma unroll
    for (int n = 0; n < 4; ++n)
      b[n] = *reinterpret_cast<const short8*>(Bs + (wn*64 + n*16 + lo) * BK + hi*8);
    #pragma unroll
    for (int m = 0; m < 2; ++m)
      #pragma unroll
      for (int n = 0; n < 4; ++n)
        acc[m][n] = mfma16(a[m], b[n], acc[m][n]);
  }

  #pragma unroll
  for (int n = 0; n < 4; ++n) {
    const int c = col0 + wn*64 + n*16 + lo;
    const float bvv = bias[c];
    #pragma unroll
    for (int m = 0; m < 2; ++m) {
      #pragma unroll
      for (int j = 0; j < 4; ++j) {
        const int r = row0 + wm*32 + m*16 + hi*4 + j;
        out[(size_t)r * D_ + c] = acc[m][n][j] + bvv;
      }
    }
  }
}

// ---------------------------------------------------------------- attention
// ROUND-2 measured structure (120.7 us): grid (S/256, B*H); 4 waves x 64
// q-rows. KV tiles of 64 staged via registers into LDS rows padded to 72
// bf16. Two barriers/tile; next-tile global loads (int4 regs) issued inside
// the compute phase -> latency hidden across the whole tile. Swapped QK^T
// (S^T = K@Q^T): q lane-local; softmax = 16 in-lane values + 2 shfl.
// NEW vs round 2: exp2-space softmax (Q pre-scaled by QSCALE) and T13
// defer-rescale (skip O/l rescale while max growth <= 8).
__global__ __launch_bounds__(256, 2) void attn_kernel(
    const bf16* __restrict__ q, const bf16* __restrict__ k,
    const bf16* __restrict__ vt, bf16* __restrict__ ao)
{
  __shared__ __align__(16) bf16 Kl[64 * 72];
  __shared__ __align__(16) bf16 Vtl[64 * 72];   // V^T tile: rows = hd

  const int tid = threadIdx.x;
  const int w = tid >> 6, l = tid & 63;
  const int lo = l & 15, hi = l >> 4;
  const int bh = blockIdx.y;
  const int q0 = blockIdx.x * 256 + w * 64;

  const bf16* kbase = k  + (size_t)bh * S_ * HD_;
  const bf16* vbase = vt + (size_t)bh * HD_ * S_;

  // Q B-frags: lane holds Q[q = n*16+lo][hd = kk*32 + hi*8 .. +8]
  short8 bq[4][2];
  const size_t qrow = (size_t)bh * S_ + q0;
  #pragma unroll
  for (int n = 0; n < 4; ++n)
    #pragma unroll
    for (int kk = 0; kk < 2; ++kk)
      bq[n][kk] = *reinterpret_cast<const short8*>(
          q + (qrow + n*16 + lo) * HD_ + kk*32 + hi*8);

  f32x4 o[4][4] = {};        // o[mm = hd-frag][n = q-frag]
  float mrun[4], lrun[4];
  #pragma unroll
  for (int n = 0; n < 4; ++n) { mrun[n] = -1.0e30f; lrun[n] = 0.0f; }

  // staging: 512 x 16B chunks per tile, 2 per thread
  const int r0 = tid >> 3,         co0 = (tid & 7) * 8;
  const int r1 = (tid + 256) >> 3, co1 = (tid & 7) * 8;

  // T14 async-STAGE split: prefetch tile kt+64 into regs before compute(kt)
  int4 kreg0, kreg1, vreg0, vreg1;
  kreg0 = *reinterpret_cast<const int4*>(kbase + (size_t)r0 * HD_ + co0);
  kreg1 = *reinterpret_cast<const int4*>(kbase + (size_t)r1 * HD_ + co1);
  vreg0 = *reinterpret_cast<const int4*>(vbase + (size_t)r0 * S_ + co0);
  vreg1 = *reinterpret_cast<const int4*>(vbase + (size_t)r1 * S_ + co1);

  for (int kt = 0; kt < S_; kt += 64) {
    __syncthreads();   // previous tile fully consumed
    *reinterpret_cast<int4*>(Kl  + r0*72 + co0) = kreg0;
    *reinterpret_cast<int4*>(Kl  + r1*72 + co1) = kreg1;
    *reinterpret_cast<int4*>(Vtl + r0*72 + co0) = vreg0;
    *reinterpret_cast<int4*>(Vtl + r1*72 + co1) = vreg1;
    if (kt + 64 < S_) {
      const int nt = kt + 64;
      kreg0 = *reinterpret_cast<const int4*>(kbase + (size_t)(nt + r0) * HD_ + co0);
      kreg1 = *reinterpret_cast<const int4*>(kbase + (size_t)(nt + r1) * HD_ + co1);
      vreg0 = *reinterpret_cast<const int4*>(vbase + (size_t)r0 * S_ + nt + co0);
      vreg1 = *reinterpret_cast<const int4*>(vbase + (size_t)r1 * S_ + nt + co1);
    }
    __syncthreads();

    // S^T = K @ Q^T
    f32x4 s[4][4] = {};
    __builtin_amdgcn_s_setprio(1);
    #pragma unroll
    for (int m = 0; m < 4; ++m) {
      short8 kf0 = *reinterpret_cast<const short8*>(Kl + (m*16+lo)*72 + hi*8);
      short8 kf1 = *reinterpret_cast<const short8*>(Kl + (m*16+lo)*72 + 32 + hi*8);
      #pragma unroll
      for (int n = 0; n < 4; ++n) {
        s[m][n] = mfma16(kf0, bq[n][0], s[m][n]);
        s[m][n] = mfma16(kf1, bq[n][1], s[m][n]);
      }
    }
    __builtin_amdgcn_s_setprio(0);

    // online softmax per q = n*16+lo (exp2 space)
    short8 pb[4][2];
    #pragma unroll
    for (int n = 0; n < 4; ++n) {
      float t0 = fmaxf(fmaxf(s[0][n][0], s[0][n][1]), s[0][n][2]);
      float t1 = fmaxf(fmaxf(s[0][n][3], s[1][n][0]), s[1][n][1]);
      float t2 = fmaxf(fmaxf(s[1][n][2], s[1][n][3]), s[2][n][0]);
      float t3 = fmaxf(fmaxf(s[2][n][1], s[2][n][2]), s[2][n][3]);
      float t4 = fmaxf(fmaxf(s[3][n][0], s[3][n][1]), s[3][n][2]);
      float mx = fmaxf(fmaxf(fmaxf(t0, t1), fmaxf(t2, t3)),
                       fmaxf(t4, s[3][n][3]));
      mx = fmaxf(mx, __shfl_xor(mx, 16, 64));
      mx = fmaxf(mx, __shfl_xor(mx, 32, 64));
      // T13 defer-rescale: skip O/l rescale while max growth <= 8 (2^8 bound)
      float mn;
      if (__all(mx <= mrun[n] + 8.0f)) {
        mn = mrun[n];
      } else {
        mn = fmaxf(mrun[n], mx);
        const float corr = exp2f(mrun[n] - mn);
        lrun[n] *= corr;
        #pragma unroll
        for (int mm = 0; mm < 4; ++mm)
          #pragma unroll
          for (int j = 0; j < 4; ++j)
            o[mm][n][j] *= corr;
        mrun[n] = mn;
      }
      float sum = 0.0f;
      #pragma unroll
      for (int m = 0; m < 4; ++m)
        #pragma unroll
        for (int j = 0; j < 4; ++j) {
          const float p = exp2f(s[m][n][j] - mn);
          s[m][n][j] = p;
          sum += p;
        }
      sum += __shfl_xor(sum, 16, 64);
      sum += __shfl_xor(sum, 32, 64);
      lrun[n] += sum;
      // pack P^T into PV B-operand: slice kk from S^T frags m=2kk, 2kk+1
      #pragma unroll
      for (int kk = 0; kk < 2; ++kk) {
        short8 t;
        t[0] = bfbits(s[2*kk][n][0]);   t[1] = bfbits(s[2*kk][n][1]);
        t[2] = bfbits(s[2*kk][n][2]);   t[3] = bfbits(s[2*kk][n][3]);
        t[4] = bfbits(s[2*kk+1][n][0]); t[5] = bfbits(s[2*kk+1][n][1]);
        t[6] = bfbits(s[2*kk+1][n][2]); t[7] = bfbits(s[2*kk+1][n][3]);
        pb[n][kk] = t;
      }
    }

    // O^T += V^T @ P^T
    __builtin_amdgcn_s_setprio(1);
    #pragma unroll
    for (int mm = 0; mm < 4; ++mm) {
      short8 vf[2];
      #pragma unroll
      for (int kk = 0; kk < 2; ++kk) {
        union { short8 v; uint2 u2[2]; } x;
        x.u2[0] = *reinterpret_cast<const uint2*>(Vtl + (mm*16+lo)*72 + kk*32 + hi*4);
        x.u2[1] = *reinterpret_cast<const uint2*>(Vtl + (mm*16+lo)*72 + kk*32 + 16 + hi*4);
        vf[kk] = x.v;
      }
      #pragma unroll
      for (int n = 0; n < 4; ++n) {
        o[mm][n] = mfma16(vf[0], pb[n][0], o[mm][n]);
        o[mm][n] = mfma16(vf[1], pb[n][1], o[mm][n]);
      }
    }
    __builtin_amdgcn_s_setprio(0);
  }

  // normalize + store O^T -> merged-head bf16 [b*S+s][h*64+hd]
  const int b = bh >> 4, h = bh & 15;
  #pragma unroll
  for (int n = 0; n < 4; ++n) {
    const float inv = 1.0f / lrun[n];
    const size_t row = (size_t)b * S_ + q0 + n*16 + lo;
    #pragma unroll
    for (int mm = 0; mm < 4; ++mm) {
      bf16 ov[4];
      #pragma unroll
      for (int j = 0; j < 4; ++j) ov[j] = (bf16)(o[mm][n][j] * inv);
      *reinterpret_cast<uint2*>(ao + row * D_ + h*64 + mm*16 + hi*4) =
          *reinterpret_cast<const uint2*>(ov);
    }
  }
}

// ---------------------------------------------------------------- launch
extern "C" void kernel_launch(void* const* d_in, const int* in_sizes, int n_in,
                              void* d_out, int out_size, void* d_ws, size_t ws_size,
                              hipStream_t stream) {
  const float* x  = (const float*)d_in[0];
  const float* wq = (const float*)d_in[1];
  const float* bq = (const float*)d_in[2];
  const float* wk = (const float*)d_in[3];
  const float* bk = (const float*)d_in[4];
  const float* wv = (const float*)d_in[5];
  const float* bv = (const float*)d_in[6];
  const float* wo = (const float*)d_in[7];
  const float* bo = (const float*)d_in[8];

  char* ws = (char*)d_ws;
  bf16* xb  = (bf16*)(ws);                           // 16 MB: x in bf16
  // wqt/wkt/wvt are contiguous -> usable as one Bt3 [3072][1024] matrix
  bf16* wqt = (bf16*)(ws + ((size_t)16 << 20));      // 2 MB: wq^T bf16
  bf16* wkt = (bf16*)(ws + ((size_t)18 << 20));      // 2 MB: wk^T bf16
  bf16* wvt = (bf16*)(ws + ((size_t)20 << 20));      // 2 MB: wv^T bf16
  bf16* wot = (bf16*)(ws + ((size_t)22 << 20));      // 2 MB: wo^T bf16
  bf16* qb  = (bf16*)(ws + ((size_t)24 << 20));      // 16 MB: q [bh][s][hd] (exp2-scaled)
  bf16* kb  = (bf16*)(ws + ((size_t)40 << 20));      // 16 MB: k [bh][s][hd]
  bf16* vtb = (bf16*)(ws + ((size_t)56 << 20));      // 16 MB: v^T [bh][hd][s]
  bf16* aob = (bf16*)(ws + ((size_t)72 << 20));      // 16 MB: attn out bf16

  convert_x_kernel<<<dim3((M_ * D_) / (256 * 8)), 256, 0, stream>>>(x, xb);

  TP p;
  p.w[0] = wq; p.w[1] = wk; p.w[2] = wv; p.w[3] = wo;
  p.wt[0] = wqt; p.wt[1] = wkt; p.wt[2] = wvt; p.wt[3] = wot;
  transpose_w_kernel<<<dim3(32, 32, 4), 256, 0, stream>>>(p);

  gemm_qkv_kernel<<<dim3(24, 64), 256, 0, stream>>>(
      xb, wqt, bq, bk, bv, qb, kb, vtb);

  attn_kernel<<<dim3(S_ / 256, B_ * H_), 256, 0, stream>>>(qb, kb, vtb, aob);

  gemm_out_kernel<<<dim3(8, 128), 256, 0, stream>>>(aob, wot, bo, (float*)d_out);
}

// Round 10
// 287.243 us; speedup vs baseline: 1.4552x; 1.1276x over previous
//
#include <hip/hip_runtime.h>
#include <hip/hip_bf16.h>

// MultiHeadSelfAttention: B=4, S=2048, D=1024, H=16, HD=64, fp32 in/out.
// bf16 MFMA. Fused QKV GEMM (8192x3072x1024), flash attention in the
// round-2 measured structure (reg-staged KV -> padded LDS, 2 barriers/tile,
// swapped QK^T, in-register P) + exp2-space softmax via RAW v_exp_f32
// (__builtin_amdgcn_exp2f -- libm exp2f was the round-8 regression) +
// defer-rescale. BM=64 out-projection GEMM.

#define B_  4
#define S_  2048
#define D_  1024
#define H_  16
#define HD_ 64
#define M_  (B_*S_)   // 8192 rows
// fold 1/sqrt(HD) and log2(e) into Q so softmax runs in exp2 space
#define QSCALE (0.125f * 1.4426950408889634f)

typedef __attribute__((ext_vector_type(8))) short short8;   // 8 x bf16
typedef __attribute__((ext_vector_type(4))) float f32x4;    // MFMA acc
typedef __hip_bfloat16 bf16;

// ---------------------------------------------------------------- helpers
__device__ inline void gload_lds16(const void* g, void* l) {
  __builtin_amdgcn_global_load_lds(
      (const __attribute__((address_space(1))) void*)g,
      (__attribute__((address_space(3))) void*)l,
      16, 0, 0);
}

__device__ inline f32x4 mfma16(short8 a, short8 b, f32x4 c) {
  return __builtin_amdgcn_mfma_f32_16x16x32_bf16(a, b, c, 0, 0, 0);
}

__device__ inline short bfbits(float f) {
  bf16 h = (bf16)f;
  return *reinterpret_cast<short*>(&h);
}

// raw v_exp_f32: 2^x, 1 VALU op (libm exp2f lowers to a multi-op OCML call)
__device__ inline float fexp2(float x) { return __builtin_amdgcn_exp2f(x); }

// ---------------------------------------------------------------- convert x
__global__ void convert_x_kernel(const float* __restrict__ x, bf16* __restrict__ xb) {
  const int i = (blockIdx.x * 256 + threadIdx.x) * 8;
  float4 a = *reinterpret_cast<const float4*>(x + i);
  float4 b = *reinterpret_cast<const float4*>(x + i + 4);
  bf16 o[8];
  o[0] = (bf16)a.x; o[1] = (bf16)a.y; o[2] = (bf16)a.z; o[3] = (bf16)a.w;
  o[4] = (bf16)b.x; o[5] = (bf16)b.y; o[6] = (bf16)b.z; o[7] = (bf16)b.w;
  *reinterpret_cast<int4*>(xb + i) = *reinterpret_cast<const int4*>(o);
}

// ------------------------------------------------- transpose + convert weights
struct TP { const float* w[4]; bf16* wt[4]; };

__global__ void transpose_w_kernel(TP p) {
  const float* w = p.w[blockIdx.z];
  bf16* wt = p.wt[blockIdx.z];
  __shared__ float t[32][33];
  const int k0 = blockIdx.y * 32, n0 = blockIdx.x * 32;
  const int c = threadIdx.x & 31, r4 = threadIdx.x >> 5;
  #pragma unroll
  for (int i = 0; i < 4; ++i) {
    int r = r4 + i * 8;
    t[r][c] = w[(size_t)(k0 + r) * D_ + n0 + c];
  }
  __syncthreads();
  #pragma unroll
  for (int i = 0; i < 4; ++i) {
    int r = r4 + i * 8;
    wt[(size_t)(n0 + r) * D_ + k0 + c] = (bf16)t[c][r];
  }
}

// ------------------------------------------------- fused QKV GEMM
// C[8192,3072] = x[8192,1024] @ Bt3[3072,1024]^T + bias; per-column routing:
// cols [0,1024)->q (scaled by QSCALE), [1024,2048)->k, [2048,3072)->v^T.
// 128x128 tile, BK=32, 4 waves (2x2), grid (24,64) = 1536 blocks (~6/CU).
__global__ __launch_bounds__(256) void gemm_qkv_kernel(
    const bf16* __restrict__ A, const bf16* __restrict__ Bt3,
    const float* __restrict__ bq, const float* __restrict__ bk,
    const float* __restrict__ bv,
    bf16* __restrict__ qb, bf16* __restrict__ kb, bf16* __restrict__ vtb)
{
  constexpr int BK = 32;
  __shared__ __align__(16) bf16 As[128 * BK];
  __shared__ __align__(16) bf16 Bs[128 * BK];
  const int tid = threadIdx.x;
  const int w = tid >> 6, l = tid & 63;
  const int lo = l & 15, hi = l >> 4;
  const int wm = w >> 1, wn = w & 1;
  const int row0 = blockIdx.y * 128;
  const int col0 = blockIdx.x * 128;

  f32x4 acc[4][4] = {};

  for (int kt = 0; kt < D_; kt += BK) {
    __syncthreads();
    #pragma unroll
    for (int i = 0; i < 2; ++i) {
      const int cb = i * 256 + w * 64;
      const int c  = cb + l;
      gload_lds16(A   + (size_t)(row0 + (c >> 2)) * D_ + kt + (c & 3) * 8,
                  (void*)(As + cb * 8));
      gload_lds16(Bt3 + (size_t)(col0 + (c >> 2)) * D_ + kt + (c & 3) * 8,
                  (void*)(Bs + cb * 8));
    }
    __syncthreads();

    short8 a[4], b[4];
    #pragma unroll
    for (int m = 0; m < 4; ++m)
      a[m] = *reinterpret_cast<const short8*>(As + (wm*64 + m*16 + lo) * BK + hi*8);
    #pragma unroll
    for (int n = 0; n < 4; ++n)
      b[n] = *reinterpret_cast<const short8*>(Bs + (wn*64 + n*16 + lo) * BK + hi*8);
    #pragma unroll
    for (int m = 0; m < 4; ++m)
      #pragma unroll
      for (int n = 0; n < 4; ++n)
        acc[m][n] = mfma16(a[m], b[n], acc[m][n]);
  }

  #pragma unroll
  for (int n = 0; n < 4; ++n) {
    const int c3 = col0 + wn*64 + n*16 + lo;          // 0..3071
    const int which = c3 >> 10;                        // 0=q 1=k 2=v (wave-uniform)
    const int cc = c3 & 1023;
    const int h = cc >> 6, hd = cc & 63;
    const float* bias = (which == 0) ? bq : (which == 1) ? bk : bv;
    const float bvv = bias[cc];
    if (which == 2) {
      // v^T: j varies s contiguously -> pack 4 bf16 into one 8B store
      #pragma unroll
      for (int m = 0; m < 4; ++m) {
        const int r = row0 + wm*64 + m*16 + hi*4;
        const int bb = r >> 11, s = r & (S_ - 1);
        bf16 ov[4];
        #pragma unroll
        for (int j = 0; j < 4; ++j) ov[j] = (bf16)(acc[m][n][j] + bvv);
        *reinterpret_cast<uint2*>(
            &vtb[((size_t)(bb * H_ + h) * HD_ + hd) * S_ + s]) =
            *reinterpret_cast<const uint2*>(ov);
      }
    } else {
      #pragma unroll
      for (int m = 0; m < 4; ++m) {
        #pragma unroll
        for (int j = 0; j < 4; ++j) {
          const int r = row0 + wm*64 + m*16 + hi*4 + j;
          const int bb = r >> 11, s = r & (S_ - 1);
          float v = acc[m][n][j] + bvv;
          if (which == 0) {
            v *= QSCALE;
            qb[((size_t)(bb * H_ + h) * S_ + s) * HD_ + hd] = (bf16)v;
          } else {
            kb[((size_t)(bb * H_ + h) * S_ + s) * HD_ + hd] = (bf16)v;
          }
        }
      }
    }
  }
}

// ------------------------------------------------- output projection GEMM
// out[8192,1024] fp32 = A[8192,1024] @ Bt^T + bias; 64x128 tile,
// grid (8,128) = 1024 blocks (~4/CU), wave tile 32x64 (2x4 frags).
__global__ __launch_bounds__(256) void gemm_out_kernel(
    const bf16* __restrict__ A, const bf16* __restrict__ Bt,
    const float* __restrict__ bias, float* __restrict__ out)
{
  constexpr int BK = 32;
  __shared__ __align__(16) bf16 As[64 * BK];
  __shared__ __align__(16) bf16 Bs[128 * BK];
  const int tid = threadIdx.x;
  const int w = tid >> 6, l = tid & 63;
  const int lo = l & 15, hi = l >> 4;
  const int wm = w >> 1, wn = w & 1;
  const int row0 = blockIdx.y * 64;
  const int col0 = blockIdx.x * 128;

  f32x4 acc[2][4] = {};

  for (int kt = 0; kt < D_; kt += BK) {
    __syncthreads();
    #pragma unroll
    for (int i = 0; i < 2; ++i) {
      const int cb = i * 256 + w * 64;
      const int c  = cb + l;
      if (i == 0)
        gload_lds16(A + (size_t)(row0 + (c >> 2)) * D_ + kt + (c & 3) * 8,
                    (void*)(As + cb * 8));
      gload_lds16(Bt + (size_t)(col0 + (c >> 2)) * D_ + kt + (c & 3) * 8,
                  (void*)(Bs + cb * 8));
    }
    __syncthreads();

    short8 a[2], b[4];
    #pragma unroll
    for (int m = 0; m < 2; ++m)
      a[m] = *reinterpret_cast<const short8*>(As + (wm*32 + m*16 + lo) * BK + hi*8);
    #pragma unroll
    for (int n = 0; n < 4; ++n)
      b[n] = *reinterpret_cast<const short8*>(Bs + (wn*64 + n*16 + lo) * BK + hi*8);
    #pragma unroll
    for (int m = 0; m < 2; ++m)
      #pragma unroll
      for (int n = 0; n < 4; ++n)
        acc[m][n] = mfma16(a[m], b[n], acc[m][n]);
  }

  #pragma unroll
  for (int n = 0; n < 4; ++n) {
    const int c = col0 + wn*64 + n*16 + lo;
    const float bvv = bias[c];
    #pragma unroll
    for (int m = 0; m < 2; ++m) {
      #pragma unroll
      for (int j = 0; j < 4; ++j) {
        const int r = row0 + wm*32 + m*16 + hi*4 + j;
        out[(size_t)r * D_ + c] = acc[m][n][j] + bvv;
      }
    }
  }
}

// ---------------------------------------------------------------- attention
// ROUND-2 measured structure: grid (S/256, B*H); 4 waves x 64 q-rows.
// KV tiles of 64 staged via registers into LDS rows padded to 72 bf16.
// Two barriers/tile; next-tile global loads issued inside the compute phase.
// Swapped QK^T (S^T = K@Q^T): q lane-local; softmax = 16 in-lane values
// + 2 shfl, exp2 space via raw v_exp_f32; T13 defer-rescale.
__global__ __launch_bounds__(256, 2) void attn_kernel(
    const bf16* __restrict__ q, const bf16* __restrict__ k,
    const bf16* __restrict__ vt, bf16* __restrict__ ao)
{
  __shared__ __align__(16) bf16 Kl[64 * 72];
  __shared__ __align__(16) bf16 Vtl[64 * 72];   // V^T tile: rows = hd

  const int tid = threadIdx.x;
  const int w = tid >> 6, l = tid & 63;
  const int lo = l & 15, hi = l >> 4;
  const int bh = blockIdx.y;
  const int q0 = blockIdx.x * 256 + w * 64;

  const bf16* kbase = k  + (size_t)bh * S_ * HD_;
  const bf16* vbase = vt + (size_t)bh * HD_ * S_;

  // Q B-frags: lane holds Q[q = n*16+lo][hd = kk*32 + hi*8 .. +8]
  short8 bq[4][2];
  const size_t qrow = (size_t)bh * S_ + q0;
  #pragma unroll
  for (int n = 0; n < 4; ++n)
    #pragma unroll
    for (int kk = 0; kk < 2; ++kk)
      bq[n][kk] = *reinterpret_cast<const short8*>(
          q + (qrow + n*16 + lo) * HD_ + kk*32 + hi*8);

  f32x4 o[4][4] = {};        // o[mm = hd-frag][n = q-frag]
  float mrun[4], lrun[4];
  #pragma unroll
  for (int n = 0; n < 4; ++n) { mrun[n] = -1.0e30f; lrun[n] = 0.0f; }

  // staging: 512 x 16B chunks per tile, 2 per thread
  const int r0 = tid >> 3,         co0 = (tid & 7) * 8;
  const int r1 = (tid + 256) >> 3, co1 = (tid & 7) * 8;

  // T14 async-STAGE split: prefetch tile kt+64 into regs before compute(kt)
  int4 kreg0, kreg1, vreg0, vreg1;
  kreg0 = *reinterpret_cast<const int4*>(kbase + (size_t)r0 * HD_ + co0);
  kreg1 = *reinterpret_cast<const int4*>(kbase + (size_t)r1 * HD_ + co1);
  vreg0 = *reinterpret_cast<const int4*>(vbase + (size_t)r0 * S_ + co0);
  vreg1 = *reinterpret_cast<const int4*>(vbase + (size_t)r1 * S_ + co1);

  for (int kt = 0; kt < S_; kt += 64) {
    __syncthreads();   // previous tile fully consumed
    *reinterpret_cast<int4*>(Kl  + r0*72 + co0) = kreg0;
    *reinterpret_cast<int4*>(Kl  + r1*72 + co1) = kreg1;
    *reinterpret_cast<int4*>(Vtl + r0*72 + co0) = vreg0;
    *reinterpret_cast<int4*>(Vtl + r1*72 + co1) = vreg1;
    if (kt + 64 < S_) {
      const int nt = kt + 64;
      kreg0 = *reinterpret_cast<const int4*>(kbase + (size_t)(nt + r0) * HD_ + co0);
      kreg1 = *reinterpret_cast<const int4*>(kbase + (size_t)(nt + r1) * HD_ + co1);
      vreg0 = *reinterpret_cast<const int4*>(vbase + (size_t)r0 * S_ + nt + co0);
      vreg1 = *reinterpret_cast<const int4*>(vbase + (size_t)r1 * S_ + nt + co1);
    }
    __syncthreads();

    // S^T = K @ Q^T
    f32x4 s[4][4] = {};
    __builtin_amdgcn_s_setprio(1);
    #pragma unroll
    for (int m = 0; m < 4; ++m) {
      short8 kf0 = *reinterpret_cast<const short8*>(Kl + (m*16+lo)*72 + hi*8);
      short8 kf1 = *reinterpret_cast<const short8*>(Kl + (m*16+lo)*72 + 32 + hi*8);
      #pragma unroll
      for (int n = 0; n < 4; ++n) {
        s[m][n] = mfma16(kf0, bq[n][0], s[m][n]);
        s[m][n] = mfma16(kf1, bq[n][1], s[m][n]);
      }
    }
    __builtin_amdgcn_s_setprio(0);

    // online softmax per q = n*16+lo (exp2 space, raw v_exp_f32)
    short8 pb[4][2];
    #pragma unroll
    for (int n = 0; n < 4; ++n) {
      float t0 = fmaxf(fmaxf(s[0][n][0], s[0][n][1]), s[0][n][2]);
      float t1 = fmaxf(fmaxf(s[0][n][3], s[1][n][0]), s[1][n][1]);
      float t2 = fmaxf(fmaxf(s[1][n][2], s[1][n][3]), s[2][n][0]);
      float t3 = fmaxf(fmaxf(s[2][n][1], s[2][n][2]), s[2][n][3]);
      float t4 = fmaxf(fmaxf(s[3][n][0], s[3][n][1]), s[3][n][2]);
      float mx = fmaxf(fmaxf(fmaxf(t0, t1), fmaxf(t2, t3)),
                       fmaxf(t4, s[3][n][3]));
      mx = fmaxf(mx, __shfl_xor(mx, 16, 64));
      mx = fmaxf(mx, __shfl_xor(mx, 32, 64));
      // T13 defer-rescale: skip O/l rescale while max growth <= 8 (2^8 bound)
      float mn;
      if (__all(mx <= mrun[n] + 8.0f)) {
        mn = mrun[n];
      } else {
        mn = fmaxf(mrun[n], mx);
        const float corr = fexp2(mrun[n] - mn);
        lrun[n] *= corr;
        #pragma unroll
        for (int mm = 0; mm < 4; ++mm)
          #pragma unroll
          for (int j = 0; j < 4; ++j)
            o[mm][n][j] *= corr;
        mrun[n] = mn;
      }
      float sum = 0.0f;
      #pragma unroll
      for (int m = 0; m < 4; ++m)
        #pragma unroll
        for (int j = 0; j < 4; ++j) {
          const float p = fexp2(s[m][n][j] - mn);
          s[m][n][j] = p;
          sum += p;
        }
      sum += __shfl_xor(sum, 16, 64);
      sum += __shfl_xor(sum, 32, 64);
      lrun[n] += sum;
      // pack P^T into PV B-operand: slice kk from S^T frags m=2kk, 2kk+1
      #pragma unroll
      for (int kk = 0; kk < 2; ++kk) {
        short8 t;
        t[0] = bfbits(s[2*kk][n][0]);   t[1] = bfbits(s[2*kk][n][1]);
        t[2] = bfbits(s[2*kk][n][2]);   t[3] = bfbits(s[2*kk][n][3]);
        t[4] = bfbits(s[2*kk+1][n][0]); t[5] = bfbits(s[2*kk+1][n][1]);
        t[6] = bfbits(s[2*kk+1][n][2]); t[7] = bfbits(s[2*kk+1][n][3]);
        pb[n][kk] = t;
      }
    }

    // O^T += V^T @ P^T
    __builtin_amdgcn_s_setprio(1);
    #pragma unroll
    for (int mm = 0; mm < 4; ++mm) {
      short8 vf[2];
      #pragma unroll
      for (int kk = 0; kk < 2; ++kk) {
        union { short8 v; uint2 u2[2]; } x;
        x.u2[0] = *reinterpret_cast<const uint2*>(Vtl + (mm*16+lo)*72 + kk*32 + hi*4);
        x.u2[1] = *reinterpret_cast<const uint2*>(Vtl + (mm*16+lo)*72 + kk*32 + 16 + hi*4);
        vf[kk] = x.v;
      }
      #pragma unroll
      for (int n = 0; n < 4; ++n) {
        o[mm][n] = mfma16(vf[0], pb[n][0], o[mm][n]);
        o[mm][n] = mfma16(vf[1], pb[n][1], o[mm][n]);
      }
    }
    __builtin_amdgcn_s_setprio(0);
  }

  // normalize + store O^T -> merged-head bf16 [b*S+s][h*64+hd]
  const int b = bh >> 4, h = bh & 15;
  #pragma unroll
  for (int n = 0; n < 4; ++n) {
    const float inv = 1.0f / lrun[n];
    const size_t row = (size_t)b * S_ + q0 + n*16 + lo;
    #pragma unroll
    for (int mm = 0; mm < 4; ++mm) {
      bf16 ov[4];
      #pragma unroll
      for (int j = 0; j < 4; ++j) ov[j] = (bf16)(o[mm][n][j] * inv);
      *reinterpret_cast<uint2*>(ao + row * D_ + h*64 + mm*16 + hi*4) =
          *reinterpret_cast<const uint2*>(ov);
    }
  }
}

// ---------------------------------------------------------------- launch
extern "C" void kernel_launch(void* const* d_in, const int* in_sizes, int n_in,
                              void* d_out, int out_size, void* d_ws, size_t ws_size,
                              hipStream_t stream) {
  const float* x  = (const float*)d_in[0];
  const float* wq = (const float*)d_in[1];
  const float* bq = (const float*)d_in[2];
  const float* wk = (const float*)d_in[3];
  const float* bk = (const float*)d_in[4];
  const float* wv = (const float*)d_in[5];
  const float* bv = (const float*)d_in[6];
  const float* wo = (const float*)d_in[7];
  const float* bo = (const float*)d_in[8];

  char* ws = (char*)d_ws;
  bf16* xb  = (bf16*)(ws);                           // 16 MB: x in bf16
  // wqt/wkt/wvt are contiguous -> usable as one Bt3 [3072][1024] matrix
  bf16* wqt = (bf16*)(ws + ((size_t)16 << 20));      // 2 MB: wq^T bf16
  bf16* wkt = (bf16*)(ws + ((size_t)18 << 20));      // 2 MB: wk^T bf16
  bf16* wvt = (bf16*)(ws + ((size_t)20 << 20));      // 2 MB: wv^T bf16
  bf16* wot = (bf16*)(ws + ((size_t)22 << 20));      // 2 MB: wo^T bf16
  bf16* qb  = (bf16*)(ws + ((size_t)24 << 20));      // 16 MB: q [bh][s][hd] (exp2-scaled)
  bf16* kb  = (bf16*)(ws + ((size_t)40 << 20));      // 16 MB: k [bh][s][hd]
  bf16* vtb = (bf16*)(ws + ((size_t)56 << 20));      // 16 MB: v^T [bh][hd][s]
  bf16* aob = (bf16*)(ws + ((size_t)72 << 20));      // 16 MB: attn out bf16

  convert_x_kernel<<<dim3((M_ * D_) / (256 * 8)), 256, 0, stream>>>(x, xb);

  TP p;
  p.w[0] = wq; p.w[1] = wk; p.w[2] = wv; p.w[3] = wo;
  p.wt[0] = wqt; p.wt[1] = wkt; p.wt[2] = wvt; p.wt[3] = wot;
  transpose_w_kernel<<<dim3(32, 32, 4), 256, 0, stream>>>(p);

  gemm_qkv_kernel<<<dim3(24, 64), 256, 0, stream>>>(
      xb, wqt, bq, bk, bv, qb, kb, vtb);

  attn_kernel<<<dim3(S_ / 256, B_ * H_), 256, 0, stream>>>(qb, kb, vtb, aob);

  gemm_out_kernel<<<dim3(8, 128), 256, 0, stream>>>(aob, wot, bo, (float*)d_out);
}